// Round 1
// baseline (271.748 us; speedup 1.0000x reference)
//
#include <hip/hip_runtime.h>
#include <math.h>

#define N_NODES 10000
#define N_EDGES 320000
#define ET (N_EDGES + N_NODES)   // edges + self-loops

// ---------------- CSR build ----------------

__global__ __launch_bounds__(256) void k_count(const int* __restrict__ ei, int* __restrict__ deg) {
  int i = blockIdx.x * 256 + threadIdx.x;
  if (i >= ET) return;
  int dst = (i < N_EDGES) ? ei[N_EDGES + i] : (i - N_EDGES);
  atomicAdd(&deg[dst], 1);
}

__global__ __launch_bounds__(1024) void k_scan(const int* __restrict__ deg, int* __restrict__ offs) {
  __shared__ int tmp[1024];
  int carry = 0;
  for (int base = 0; base < N_NODES; base += 1024) {
    int i = base + (int)threadIdx.x;
    int v = (i < N_NODES) ? deg[i] : 0;
    int acc = v;
    tmp[threadIdx.x] = acc;
    __syncthreads();
    for (int off = 1; off < 1024; off <<= 1) {
      int t = (threadIdx.x >= (unsigned)off) ? tmp[threadIdx.x - off] : 0;
      __syncthreads();
      acc += t;
      tmp[threadIdx.x] = acc;
      __syncthreads();
    }
    int total = tmp[1023];
    if (i < N_NODES) offs[i] = carry + acc - v;   // exclusive
    carry += total;
    __syncthreads();
  }
  if (threadIdx.x == 0) offs[N_NODES] = carry;
}

__global__ __launch_bounds__(256) void k_scatter(const int* __restrict__ ei, const int* __restrict__ offs,
                                                 int* __restrict__ cursor, int* __restrict__ csr_src) {
  int i = blockIdx.x * 256 + threadIdx.x;
  if (i >= ET) return;
  int src, dst;
  if (i < N_EDGES) { src = ei[i]; dst = ei[N_EDGES + i]; }
  else             { src = dst = i - N_EDGES; }
  int pos = offs[dst] + atomicAdd(&cursor[dst], 1);
  csr_src[pos] = src;
}

// ---------------- layer 1 ----------------

#define G1_ROWS 16
__global__ __launch_bounds__(320) void k_gemm1(const float* __restrict__ x, const float* __restrict__ W1,
                                               float* __restrict__ h1) {
  __shared__ float xs[G1_ROWS][128];
  int r0 = blockIdx.x * G1_ROWS;
  for (int t = threadIdx.x; t < G1_ROWS * 128; t += 320) {
    int r = t >> 7, k = t & 127;
    int gr = r0 + r;
    xs[r][k] = (gr < N_NODES) ? x[gr * 128 + k] : 0.f;
  }
  __syncthreads();
  int j = threadIdx.x;  // 0..319 output column
  float acc[G1_ROWS];
#pragma unroll
  for (int r = 0; r < G1_ROWS; ++r) acc[r] = 0.f;
  for (int k = 0; k < 128; k += 4) {
    float w0 = W1[(k + 0) * 320 + j];
    float w1 = W1[(k + 1) * 320 + j];
    float w2 = W1[(k + 2) * 320 + j];
    float w3 = W1[(k + 3) * 320 + j];
#pragma unroll
    for (int r = 0; r < G1_ROWS; ++r) {
      float4 xv = *reinterpret_cast<const float4*>(&xs[r][k]);
      acc[r] = fmaf(xv.x, w0, acc[r]);
      acc[r] = fmaf(xv.y, w1, acc[r]);
      acc[r] = fmaf(xv.z, w2, acc[r]);
      acc[r] = fmaf(xv.w, w3, acc[r]);
    }
  }
#pragma unroll
  for (int r = 0; r < G1_ROWS; ++r) {
    int gr = r0 + r;
    if (gr < N_NODES) h1[gr * 320 + j] = acc[r];
  }
}

__global__ __launch_bounds__(320) void k_att1(const float* __restrict__ h1, const float* __restrict__ att_src,
                                              const float* __restrict__ att_dst,
                                              float* __restrict__ a_src, float* __restrict__ a_dst) {
  int n = blockIdx.x;
  int h = threadIdx.x >> 6, c = threadIdx.x & 63;
  float v = h1[n * 320 + h * 64 + c];
  float vs = v * att_src[h * 64 + c];
  float vd = v * att_dst[h * 64 + c];
  for (int off = 32; off; off >>= 1) {
    vs += __shfl_down(vs, off);
    vd += __shfl_down(vd, off);
  }
  if (c == 0) { a_src[n * 5 + h] = vs; a_dst[n * 5 + h] = vd; }
}

// one block per dst node; wave h handles head h, lane = channel
__global__ __launch_bounds__(320) void k_agg1(const float* __restrict__ h1, const float* __restrict__ a_src,
                                              const float* __restrict__ a_dst, const float* __restrict__ b1,
                                              const int* __restrict__ offs, const int* __restrict__ csr_src,
                                              float* __restrict__ out1) {
  int n = blockIdx.x;
  int h = threadIdx.x >> 6, c = threadIdx.x & 63;
  int beg = offs[n], end = offs[n + 1];
  float adn = a_dst[n * 5 + h];
  float s = 0.f, acc = 0.f;
  for (int e = beg; e < end; ++e) {
    int src = csr_src[e];
    float el = a_src[src * 5 + h] + adn;
    el = (el > 0.f) ? el : 0.2f * el;      // leaky_relu
    float p = __expf(el);                  // logits are O(+-5): no max-shift needed
    s += p;
    acc = fmaf(p, h1[src * 320 + h * 64 + c], acc);
  }
  float o = acc / (s + 1e-16f) + b1[h * 64 + c];
  out1[n * 320 + h * 64 + c] = fmaxf(o, 0.f);   // + bias, ReLU
}

// ---------------- layer 2 ----------------

#define G2_ROWS 16
__global__ __launch_bounds__(256) void k_gemm2(const float* __restrict__ out1, const float* __restrict__ W2,
                                               float* __restrict__ h2) {
  __shared__ float xs[G2_ROWS][320];
  int r0 = blockIdx.x * G2_ROWS;
  for (int t = threadIdx.x; t < G2_ROWS * 320; t += 256) {
    int r = t / 320, k = t % 320;
    int gr = r0 + r;
    xs[r][k] = (gr < N_NODES) ? out1[gr * 320 + k] : 0.f;
  }
  __syncthreads();
  int j = threadIdx.x & 63;
  int g = threadIdx.x >> 6;   // 4 row-groups of 4 rows
  float acc[4] = {0.f, 0.f, 0.f, 0.f};
  for (int k = 0; k < 320; k += 4) {
    float w0 = W2[(k + 0) * 64 + j];
    float w1 = W2[(k + 1) * 64 + j];
    float w2v = W2[(k + 2) * 64 + j];
    float w3 = W2[(k + 3) * 64 + j];
#pragma unroll
    for (int r = 0; r < 4; ++r) {
      float4 xv = *reinterpret_cast<const float4*>(&xs[g * 4 + r][k]);
      acc[r] = fmaf(xv.x, w0, fmaf(xv.y, w1, fmaf(xv.z, w2v, fmaf(xv.w, w3, acc[r]))));
    }
  }
#pragma unroll
  for (int r = 0; r < 4; ++r) {
    int gr = r0 + g * 4 + r;
    if (gr < N_NODES) h2[gr * 64 + j] = acc[r];
  }
}

__global__ __launch_bounds__(256) void k_att2(const float* __restrict__ h2, const float* __restrict__ att_src,
                                              const float* __restrict__ att_dst,
                                              float* __restrict__ a_src, float* __restrict__ a_dst) {
  int n = blockIdx.x * 4 + (threadIdx.x >> 6);
  int c = threadIdx.x & 63;
  if (n >= N_NODES) return;
  float v = h2[n * 64 + c];
  float vs = v * att_src[c], vd = v * att_dst[c];
  for (int off = 32; off; off >>= 1) {
    vs += __shfl_down(vs, off);
    vd += __shfl_down(vd, off);
  }
  if (c == 0) { a_src[n] = vs; a_dst[n] = vd; }
}

__global__ __launch_bounds__(256) void k_agg2(const float* __restrict__ h2, const float* __restrict__ a_src,
                                              const float* __restrict__ a_dst, const float* __restrict__ b2,
                                              const int* __restrict__ offs, const int* __restrict__ csr_src,
                                              float* __restrict__ out) {
  int n = blockIdx.x * 4 + (threadIdx.x >> 6);
  int c = threadIdx.x & 63;
  if (n >= N_NODES) return;
  int beg = offs[n], end = offs[n + 1];
  float adn = a_dst[n];
  float s = 0.f, acc = 0.f;
  for (int e = beg; e < end; ++e) {
    int src = csr_src[e];
    float el = a_src[src] + adn;
    el = (el > 0.f) ? el : 0.2f * el;
    float p = __expf(el);
    s += p;
    acc = fmaf(p, h2[src * 64 + c], acc);
  }
  float o = acc / (s + 1e-16f) + b2[c];
  out[n * 64 + c] = fmaxf(o, 0.f);
}

// ---------------- launch ----------------

extern "C" void kernel_launch(void* const* d_in, const int* in_sizes, int n_in,
                              void* d_out, int out_size, void* d_ws, size_t ws_size,
                              hipStream_t stream) {
  const float* x    = (const float*)d_in[0];
  const int*   ei   = (const int*)d_in[1];     // [2, E] int32
  const float* W1   = (const float*)d_in[2];
  const float* as1w = (const float*)d_in[3];
  const float* ad1w = (const float*)d_in[4];
  const float* b1   = (const float*)d_in[5];
  const float* W2   = (const float*)d_in[6];
  const float* as2w = (const float*)d_in[7];
  const float* ad2w = (const float*)d_in[8];
  const float* b2   = (const float*)d_in[9];
  float* out = (float*)d_out;

  char* ws = (char*)d_ws;
  size_t off = 0;
  auto alloc = [&](size_t bytes) -> void* {
    void* p = ws + off;
    off += (bytes + 255) & ~(size_t)255;
    return p;
  };
  float* h1     = (float*)alloc((size_t)N_NODES * 320 * 4);
  float* out1   = (float*)alloc((size_t)N_NODES * 320 * 4);
  float* h2     = (float*)alloc((size_t)N_NODES * 64 * 4);
  float* a_src1 = (float*)alloc((size_t)N_NODES * 5 * 4);
  float* a_dst1 = (float*)alloc((size_t)N_NODES * 5 * 4);
  float* a_src2 = (float*)alloc((size_t)N_NODES * 4);
  float* a_dst2 = (float*)alloc((size_t)N_NODES * 4);
  int*   deg    = (int*)alloc((size_t)N_NODES * 4);
  int*   cursor = (int*)alloc((size_t)N_NODES * 4);
  int*   offs   = (int*)alloc((size_t)(N_NODES + 1) * 4);
  int*   csr    = (int*)alloc((size_t)ET * 4);

  hipMemsetAsync(deg, 0, (size_t)N_NODES * 4, stream);
  hipMemsetAsync(cursor, 0, (size_t)N_NODES * 4, stream);

  k_count  <<<(ET + 255) / 256, 256, 0, stream>>>(ei, deg);
  k_scan   <<<1, 1024, 0, stream>>>(deg, offs);
  k_scatter<<<(ET + 255) / 256, 256, 0, stream>>>(ei, offs, cursor, csr);

  k_gemm1  <<<(N_NODES + G1_ROWS - 1) / G1_ROWS, 320, 0, stream>>>(x, W1, h1);
  k_att1   <<<N_NODES, 320, 0, stream>>>(h1, as1w, ad1w, a_src1, a_dst1);
  k_agg1   <<<N_NODES, 320, 0, stream>>>(h1, a_src1, a_dst1, b1, offs, csr, out1);

  k_gemm2  <<<(N_NODES + G2_ROWS - 1) / G2_ROWS, 256, 0, stream>>>(out1, W2, h2);
  k_att2   <<<(N_NODES + 3) / 4, 256, 0, stream>>>(h2, as2w, ad2w, a_src2, a_dst2);
  k_agg2   <<<(N_NODES + 3) / 4, 256, 0, stream>>>(h2, a_src2, a_dst2, b2, offs, csr, out);
}

// Round 2
// 195.280 us; speedup vs baseline: 1.3916x; 1.3916x over previous
//
#include <hip/hip_runtime.h>
#include <math.h>

#define N_NODES 10000
#define N_EDGES 320000
#define ET (N_EDGES + N_NODES)   // edges + self-loops

__device__ __forceinline__ float lrelu_exp(float e) {
  e = (e > 0.f) ? e : 0.2f * e;   // leaky_relu
  return __expf(e);               // logits O(+-5): no max-shift needed
}

// ---------------- CSR build ----------------

__global__ __launch_bounds__(256) void k_count(const int* __restrict__ ei, int* __restrict__ deg) {
  int i = blockIdx.x * 256 + threadIdx.x;
  if (i >= ET) return;
  int dst = (i < N_EDGES) ? ei[N_EDGES + i] : (i - N_EDGES);
  atomicAdd(&deg[dst], 1);
}

__global__ __launch_bounds__(1024) void k_scan(const int* __restrict__ deg, int* __restrict__ offs) {
  __shared__ int wsum[16];
  __shared__ int carry_s;
  int lane = threadIdx.x & 63, wid = threadIdx.x >> 6;
  if (threadIdx.x == 0) carry_s = 0;
  __syncthreads();
  for (int base = 0; base < N_NODES; base += 1024) {
    int i = base + (int)threadIdx.x;
    int v = (i < N_NODES) ? deg[i] : 0;
    int acc = v;                        // inclusive scan within wave
#pragma unroll
    for (int off = 1; off < 64; off <<= 1) {
      int t = __shfl_up(acc, off);
      if (lane >= off) acc += t;
    }
    if (lane == 63) wsum[wid] = acc;
    __syncthreads();
    if (wid == 0 && lane < 16) {        // exclusive scan of 16 wave sums
      int w = wsum[lane];
      int a2 = w;
#pragma unroll
      for (int off = 1; off < 16; off <<= 1) {
        int t = __shfl_up(a2, off);
        if (lane >= off) a2 += t;
      }
      wsum[lane] = a2 - w;
    }
    __syncthreads();
    int carry = carry_s;
    if (i < N_NODES) offs[i] = carry + wsum[wid] + acc - v;
    __syncthreads();                    // everyone read carry_s before update
    if (threadIdx.x == 1023) carry_s = carry + wsum[15] + acc;
  }
  __syncthreads();
  if (threadIdx.x == 0) offs[N_NODES] = carry_s;
}

__global__ __launch_bounds__(256) void k_scatter(const int* __restrict__ ei, const int* __restrict__ offs,
                                                 int* __restrict__ cursor, int* __restrict__ csr_src) {
  int i = blockIdx.x * 256 + threadIdx.x;
  if (i >= ET) return;
  int src, dst;
  if (i < N_EDGES) { src = ei[i]; dst = ei[N_EDGES + i]; }
  else             { src = dst = i - N_EDGES; }
  int pos = offs[dst] + atomicAdd(&cursor[dst], 1);
  csr_src[pos] = src;
}

// ---------------- layer 1 ----------------

#define G1_ROWS 16
__global__ __launch_bounds__(320) void k_gemm1(const float* __restrict__ x, const float* __restrict__ W1,
                                               float* __restrict__ h1) {
  __shared__ float xs[G1_ROWS][128];
  int r0 = blockIdx.x * G1_ROWS;
  for (int t = threadIdx.x; t < G1_ROWS * 128; t += 320) {
    int r = t >> 7, k = t & 127;
    int gr = r0 + r;
    xs[r][k] = (gr < N_NODES) ? x[gr * 128 + k] : 0.f;
  }
  __syncthreads();
  int j = threadIdx.x;  // 0..319 output column
  float acc[G1_ROWS];
#pragma unroll
  for (int r = 0; r < G1_ROWS; ++r) acc[r] = 0.f;
  for (int k = 0; k < 128; k += 4) {
    float w0 = W1[(k + 0) * 320 + j];
    float w1 = W1[(k + 1) * 320 + j];
    float w2 = W1[(k + 2) * 320 + j];
    float w3 = W1[(k + 3) * 320 + j];
#pragma unroll
    for (int r = 0; r < G1_ROWS; ++r) {
      float4 xv = *reinterpret_cast<const float4*>(&xs[r][k]);
      acc[r] = fmaf(xv.x, w0, acc[r]);
      acc[r] = fmaf(xv.y, w1, acc[r]);
      acc[r] = fmaf(xv.z, w2, acc[r]);
      acc[r] = fmaf(xv.w, w3, acc[r]);
    }
  }
#pragma unroll
  for (int r = 0; r < G1_ROWS; ++r) {
    int gr = r0 + r;
    if (gr < N_NODES) h1[gr * 320 + j] = acc[r];
  }
}

__global__ __launch_bounds__(320) void k_att1(const float* __restrict__ h1, const float* __restrict__ att_src,
                                              const float* __restrict__ att_dst,
                                              float* __restrict__ a_src, float* __restrict__ a_dst) {
  int n = blockIdx.x;
  int h = threadIdx.x >> 6, c = threadIdx.x & 63;
  float v = h1[n * 320 + h * 64 + c];
  float vs = v * att_src[h * 64 + c];
  float vd = v * att_dst[h * 64 + c];
  for (int off = 32; off; off >>= 1) {
    vs += __shfl_down(vs, off);
    vd += __shfl_down(vd, off);
  }
  if (c == 0) { a_src[n * 5 + h] = vs; a_dst[n * 5 + h] = vd; }
}

// head-split aggregation: blockIdx.y = head (head-major in time -> per-head
// h1 slice is 2.56 MB, fits each XCD's 4 MB L2). One wave per (node, head).
__global__ __launch_bounds__(256) void k_agg1(const float* __restrict__ h1, const float* __restrict__ a_src,
                                              const float* __restrict__ a_dst, const float* __restrict__ b1,
                                              const int* __restrict__ offs, const int* __restrict__ csr_src,
                                              float* __restrict__ out1) {
  int n = blockIdx.x * 4 + (threadIdx.x >> 6);
  if (n >= N_NODES) return;
  int h = blockIdx.y;
  int c = threadIdx.x & 63;
  int beg = offs[n], end = offs[n + 1];
  float adn = a_dst[n * 5 + h];
  const float* __restrict__ hh = h1 + h * 64 + c;
  const float* __restrict__ as = a_src + h;
  float s = 0.f, acc = 0.f;
  int e = beg;
  for (; e + 4 <= end; e += 4) {            // 4 independent gather chains
    int s0 = csr_src[e], s1 = csr_src[e + 1], s2 = csr_src[e + 2], s3 = csr_src[e + 3];
    float p0 = lrelu_exp(as[s0 * 5] + adn);
    float p1 = lrelu_exp(as[s1 * 5] + adn);
    float p2 = lrelu_exp(as[s2 * 5] + adn);
    float p3 = lrelu_exp(as[s3 * 5] + adn);
    float g0 = hh[s0 * 320], g1 = hh[s1 * 320], g2 = hh[s2 * 320], g3 = hh[s3 * 320];
    s += (p0 + p1) + (p2 + p3);
    acc = fmaf(p0, g0, acc);
    acc = fmaf(p1, g1, acc);
    acc = fmaf(p2, g2, acc);
    acc = fmaf(p3, g3, acc);
  }
  for (; e < end; ++e) {
    int s0 = csr_src[e];
    float p0 = lrelu_exp(as[s0 * 5] + adn);
    s += p0;
    acc = fmaf(p0, hh[s0 * 320], acc);
  }
  float o = acc / (s + 1e-16f) + b1[h * 64 + c];
  out1[n * 320 + h * 64 + c] = fmaxf(o, 0.f);   // + bias, ReLU
}

// ---------------- layer 2 ----------------

#define G2_ROWS 16
__global__ __launch_bounds__(256) void k_gemm2(const float* __restrict__ out1, const float* __restrict__ W2,
                                               float* __restrict__ h2) {
  __shared__ float xs[G2_ROWS][320];
  int r0 = blockIdx.x * G2_ROWS;
  for (int t = threadIdx.x; t < G2_ROWS * 320; t += 256) {
    int r = t / 320, k = t % 320;
    int gr = r0 + r;
    xs[r][k] = (gr < N_NODES) ? out1[gr * 320 + k] : 0.f;
  }
  __syncthreads();
  int j = threadIdx.x & 63;
  int g = threadIdx.x >> 6;   // 4 row-groups of 4 rows
  float acc[4] = {0.f, 0.f, 0.f, 0.f};
  for (int k = 0; k < 320; k += 4) {
    float w0 = W2[(k + 0) * 64 + j];
    float w1 = W2[(k + 1) * 64 + j];
    float w2v = W2[(k + 2) * 64 + j];
    float w3 = W2[(k + 3) * 64 + j];
#pragma unroll
    for (int r = 0; r < 4; ++r) {
      float4 xv = *reinterpret_cast<const float4*>(&xs[g * 4 + r][k]);
      acc[r] = fmaf(xv.x, w0, fmaf(xv.y, w1, fmaf(xv.z, w2v, fmaf(xv.w, w3, acc[r]))));
    }
  }
#pragma unroll
  for (int r = 0; r < 4; ++r) {
    int gr = r0 + g * 4 + r;
    if (gr < N_NODES) h2[gr * 64 + j] = acc[r];
  }
}

__global__ __launch_bounds__(256) void k_att2(const float* __restrict__ h2, const float* __restrict__ att_src,
                                              const float* __restrict__ att_dst,
                                              float* __restrict__ a_src, float* __restrict__ a_dst) {
  int n = blockIdx.x * 4 + (threadIdx.x >> 6);
  int c = threadIdx.x & 63;
  if (n >= N_NODES) return;
  float v = h2[n * 64 + c];
  float vs = v * att_src[c], vd = v * att_dst[c];
  for (int off = 32; off; off >>= 1) {
    vs += __shfl_down(vs, off);
    vd += __shfl_down(vd, off);
  }
  if (c == 0) { a_src[n] = vs; a_dst[n] = vd; }
}

__global__ __launch_bounds__(256) void k_agg2(const float* __restrict__ h2, const float* __restrict__ a_src,
                                              const float* __restrict__ a_dst, const float* __restrict__ b2,
                                              const int* __restrict__ offs, const int* __restrict__ csr_src,
                                              float* __restrict__ out) {
  int n = blockIdx.x * 4 + (threadIdx.x >> 6);
  int c = threadIdx.x & 63;
  if (n >= N_NODES) return;
  int beg = offs[n], end = offs[n + 1];
  float adn = a_dst[n];
  float s = 0.f, acc = 0.f;
  int e = beg;
  for (; e + 4 <= end; e += 4) {
    int s0 = csr_src[e], s1 = csr_src[e + 1], s2 = csr_src[e + 2], s3 = csr_src[e + 3];
    float p0 = lrelu_exp(a_src[s0] + adn);
    float p1 = lrelu_exp(a_src[s1] + adn);
    float p2 = lrelu_exp(a_src[s2] + adn);
    float p3 = lrelu_exp(a_src[s3] + adn);
    float g0 = h2[s0 * 64 + c], g1 = h2[s1 * 64 + c], g2 = h2[s2 * 64 + c], g3 = h2[s3 * 64 + c];
    s += (p0 + p1) + (p2 + p3);
    acc = fmaf(p0, g0, acc);
    acc = fmaf(p1, g1, acc);
    acc = fmaf(p2, g2, acc);
    acc = fmaf(p3, g3, acc);
  }
  for (; e < end; ++e) {
    int s0 = csr_src[e];
    float p0 = lrelu_exp(a_src[s0] + adn);
    s += p0;
    acc = fmaf(p0, h2[s0 * 64 + c], acc);
  }
  float o = acc / (s + 1e-16f) + b2[c];
  out[n * 64 + c] = fmaxf(o, 0.f);
}

// ---------------- launch ----------------

extern "C" void kernel_launch(void* const* d_in, const int* in_sizes, int n_in,
                              void* d_out, int out_size, void* d_ws, size_t ws_size,
                              hipStream_t stream) {
  const float* x    = (const float*)d_in[0];
  const int*   ei   = (const int*)d_in[1];
  const float* W1   = (const float*)d_in[2];
  const float* as1w = (const float*)d_in[3];
  const float* ad1w = (const float*)d_in[4];
  const float* b1   = (const float*)d_in[5];
  const float* W2   = (const float*)d_in[6];
  const float* as2w = (const float*)d_in[7];
  const float* ad2w = (const float*)d_in[8];
  const float* b2   = (const float*)d_in[9];
  float* out = (float*)d_out;

  char* ws = (char*)d_ws;
  size_t off = 0;
  auto alloc = [&](size_t bytes) -> void* {
    void* p = ws + off;
    off += (bytes + 255) & ~(size_t)255;
    return p;
  };
  float* h1     = (float*)alloc((size_t)N_NODES * 320 * 4);
  float* out1   = (float*)alloc((size_t)N_NODES * 320 * 4);
  float* h2     = (float*)alloc((size_t)N_NODES * 64 * 4);
  float* a_src1 = (float*)alloc((size_t)N_NODES * 5 * 4);
  float* a_dst1 = (float*)alloc((size_t)N_NODES * 5 * 4);
  float* a_src2 = (float*)alloc((size_t)N_NODES * 4);
  float* a_dst2 = (float*)alloc((size_t)N_NODES * 4);
  int*   deg    = (int*)alloc((size_t)N_NODES * 4);
  int*   cursor = (int*)alloc((size_t)N_NODES * 4);
  int*   offs   = (int*)alloc((size_t)(N_NODES + 1) * 4);
  int*   csr    = (int*)alloc((size_t)ET * 4);

  hipMemsetAsync(deg, 0, (size_t)N_NODES * 4, stream);
  hipMemsetAsync(cursor, 0, (size_t)N_NODES * 4, stream);

  k_count  <<<(ET + 255) / 256, 256, 0, stream>>>(ei, deg);
  k_scan   <<<1, 1024, 0, stream>>>(deg, offs);
  k_scatter<<<(ET + 255) / 256, 256, 0, stream>>>(ei, offs, cursor, csr);

  k_gemm1  <<<(N_NODES + G1_ROWS - 1) / G1_ROWS, 320, 0, stream>>>(x, W1, h1);
  k_att1   <<<N_NODES, 320, 0, stream>>>(h1, as1w, ad1w, a_src1, a_dst1);
  {
    dim3 grid((N_NODES + 3) / 4, 5);
    k_agg1 <<<grid, 256, 0, stream>>>(h1, a_src1, a_dst1, b1, offs, csr, out1);
  }

  k_gemm2  <<<(N_NODES + G2_ROWS - 1) / G2_ROWS, 256, 0, stream>>>(out1, W2, h2);
  k_att2   <<<(N_NODES + 3) / 4, 256, 0, stream>>>(h2, as2w, ad2w, a_src2, a_dst2);
  k_agg2   <<<(N_NODES + 3) / 4, 256, 0, stream>>>(h2, a_src2, a_dst2, b2, offs, csr, out);
}